// Round 5
// baseline (1236.257 us; speedup 1.0000x reference)
//
#include <hip/hip_runtime.h>
#include <math.h>

// RUNG confidence-lambda QN-IRLS, round 5: occupancy push.
// Single change vs r4: NSPLIT 16->32 (2048 blocks = 8 blocks/CU = 32 waves/CU),
// __launch_bounds__(256,8) pins VGPR<=64. JT_PER=2.

#define NN 4096
#define DIN 512
#define HID 256
#define CD 64
#define NSPLIT 32
#define JT_PER 2   // (NN/NSPLIT)/64

static constexpr float SCAD_Af   = 3.7f;
static constexpr float EPSf      = 1e-6f;
static constexpr float DIST_EPSf = 1e-8f;
#define LAM_BASEF ((float)(1.0 / 0.9 - 1.0))

typedef __attribute__((ext_vector_type(8))) short bf16x8;
typedef __attribute__((ext_vector_type(4))) float f32x4;

#define MFMA16(a, b, c) __builtin_amdgcn_mfma_f32_16x16x32_bf16((a), (b), (c), 0, 0, 0)

__device__ inline unsigned short f2bf(float f) {
    unsigned u = __float_as_uint(f);
    u += 0x7FFFu + ((u >> 16) & 1u);          // RNE
    return (unsigned short)(u >> 16);
}
__device__ inline float bf2f(unsigned short h) {
    return __uint_as_float(((unsigned)h) << 16);
}

// ---------------- GEMM1: Hid = relu(X @ W1 + b1) ----------------
__global__ __launch_bounds__(256) void k_gemm1(const float* __restrict__ X,
    const float* __restrict__ W1, const float* __restrict__ b1,
    float* __restrict__ Hid)
{
    __shared__ float Xs[16][68];
    __shared__ float Ws[16][68];
    const int tid = threadIdx.x;
    const int tx = tid & 15, ty = tid >> 4;
    const int M0 = blockIdx.x * 64, N0 = blockIdx.y * 64;
    float acc[4][4] = {};
    for (int k0 = 0; k0 < DIN; k0 += 16) {
        __syncthreads();
        {
            const int kk = tid & 15, mm = tid >> 4;
            #pragma unroll
            for (int r = 0; r < 4; ++r)
                Xs[kk][mm + 16*r] = X[(size_t)(M0 + mm + 16*r) * DIN + k0 + kk];
            const int n = tid & 63, kw = tid >> 6;
            #pragma unroll
            for (int r = 0; r < 4; ++r)
                Ws[kw + 4*r][n] = W1[(size_t)(k0 + kw + 4*r) * HID + N0 + n];
        }
        __syncthreads();
        #pragma unroll
        for (int kk = 0; kk < 16; ++kk) {
            const float4 av = *(const float4*)&Xs[kk][4*ty];
            const float4 bv = *(const float4*)&Ws[kk][4*tx];
            const float a[4] = {av.x, av.y, av.z, av.w};
            const float b[4] = {bv.x, bv.y, bv.z, bv.w};
            #pragma unroll
            for (int i = 0; i < 4; ++i)
                #pragma unroll
                for (int j = 0; j < 4; ++j)
                    acc[i][j] = fmaf(a[i], b[j], acc[i][j]);
        }
    }
    #pragma unroll
    for (int i = 0; i < 4; ++i)
        #pragma unroll
        for (int j = 0; j < 4; ++j) {
            const int gn = N0 + 4*tx + j;
            const float v = acc[i][j] + b1[gn];
            Hid[(size_t)(M0 + 4*ty + i) * HID + gn] = fmaxf(v, 0.0f);
        }
}

// ---------------- GEMM2: F0 = Hid @ W2 + b2 ----------------
__global__ __launch_bounds__(256) void k_gemm2(const float* __restrict__ Hd,
    const float* __restrict__ W2, const float* __restrict__ b2,
    float* __restrict__ F0)
{
    __shared__ float Hs[16][68];
    __shared__ float Ws[16][68];
    const int tid = threadIdx.x;
    const int tx = tid & 15, ty = tid >> 4;
    const int M0 = blockIdx.x * 64;
    float acc[4][4] = {};
    for (int k0 = 0; k0 < HID; k0 += 16) {
        __syncthreads();
        {
            const int kk = tid & 15, mm = tid >> 4;
            #pragma unroll
            for (int r = 0; r < 4; ++r)
                Hs[kk][mm + 16*r] = Hd[(size_t)(M0 + mm + 16*r) * HID + k0 + kk];
            const int n = tid & 63, kw = tid >> 6;
            #pragma unroll
            for (int r = 0; r < 4; ++r)
                Ws[kw + 4*r][n] = W2[(size_t)(k0 + kw + 4*r) * CD + n];
        }
        __syncthreads();
        #pragma unroll
        for (int kk = 0; kk < 16; ++kk) {
            const float4 av = *(const float4*)&Hs[kk][4*ty];
            const float4 bv = *(const float4*)&Ws[kk][4*tx];
            const float a[4] = {av.x, av.y, av.z, av.w};
            const float b[4] = {bv.x, bv.y, bv.z, bv.w};
            #pragma unroll
            for (int i = 0; i < 4; ++i)
                #pragma unroll
                for (int j = 0; j < 4; ++j)
                    acc[i][j] = fmaf(a[i], b[j], acc[i][j]);
        }
    }
    #pragma unroll
    for (int i = 0; i < 4; ++i)
        #pragma unroll
        for (int j = 0; j < 4; ++j) {
            const int gn = 4*tx + j;
            F0[(size_t)(M0 + 4*ty + i) * CD + gn] = acc[i][j] + b2[gn];
        }
}

// ---------------- conf -> raw_lam ----------------
__global__ __launch_bounds__(256) void k_conf(const float* __restrict__ F0,
    const float* __restrict__ raw_alpha, float* __restrict__ raw_lam)
{
    const int lane = threadIdx.x & 63;
    const int row  = blockIdx.x * 4 + (threadIdx.x >> 6);
    const float alpha = log1pf(expf(raw_alpha[0])) + 0.5f;
    const float f = F0[(size_t)row * CD + lane];
    float m = f;
    #pragma unroll
    for (int o = 32; o > 0; o >>= 1) m = fmaxf(m, __shfl_xor(m, o, 64));
    float e = expf(f - m);
    #pragma unroll
    for (int o = 32; o > 0; o >>= 1) e += __shfl_xor(e, o, 64);
    float conf = 1.0f / e;
    conf = fminf(fmaxf(conf, EPSf), 1.0f - EPSf);
    const float rl = LAM_BASEF * powf(fmaxf(1.0f - conf, EPSf), alpha);
    if (lane == 0) raw_lam[row] = rl;
}

// ---------------- lam_node ----------------
__global__ __launch_bounds__(256) void k_lam(const float* __restrict__ raw_lam,
    float* __restrict__ lam_node)
{
    __shared__ float red[256];
    float s = 0.0f;
    for (int i = threadIdx.x; i < NN; i += 256) s += raw_lam[i];
    red[threadIdx.x] = s;
    __syncthreads();
    for (int o = 128; o > 0; o >>= 1) {
        if (threadIdx.x < o) red[threadIdx.x] += red[threadIdx.x + o];
        __syncthreads();
    }
    const float mean  = red[0] * (1.0f / NN);
    const float scale = LAM_BASEF / fmaxf(mean, EPSf);
    for (int i = threadIdx.x; i < NN; i += 256)
        lam_node[i] = fmaxf(raw_lam[i] * scale, EPSf);
}

// ---------------- deg -> u = 1/sqrt(rowsum(A)+1) ----------------
__global__ __launch_bounds__(256) void k_deg(const float* __restrict__ A,
    float* __restrict__ u)
{
    __shared__ float red[256];
    const int i = blockIdx.x;
    float s = 0.0f;
    for (int j = threadIdx.x; j < NN; j += 256) s += A[(size_t)i * NN + j];
    red[threadIdx.x] = s;
    __syncthreads();
    for (int o = 128; o > 0; o >>= 1) {
        if (threadIdx.x < o) red[threadIdx.x] += red[threadIdx.x + o];
        __syncthreads();
    }
    if (threadIdx.x == 0) u[i] = 1.0f / sqrtf(red[0] + 1.0f);
}

// ---------------- one-time A -> bf16 cast, permuted into MFMA C-fragment order ----
// tile (ti,tj) 64x64; element (r,c) -> pos = ((r>>2)*16 + (c&15))*16 + (c>>4)*4 + (r&3)
__global__ __launch_bounds__(256) void k_castA(const float* __restrict__ A,
    unsigned short* __restrict__ Abf)
{
    __shared__ unsigned short t_lds[4096];
    const int ti = blockIdx.x >> 6, tj = blockIdx.x & 63;
    const int t = threadIdx.x;
    const int r = t >> 2, cq = t & 3;
    const size_t arow = (size_t)(ti * 64 + r) * NN + tj * 64 + cq * 16;
    #pragma unroll
    for (int q = 0; q < 4; ++q) {
        const float4 v = *(const float4*)(A + arow + 4 * q);
        const float vv[4] = {v.x, v.y, v.z, v.w};
        #pragma unroll
        for (int e = 0; e < 4; ++e) {
            const int cc = 4 * q + e;                       // c & 15
            const int pos = ((r >> 2) * 16 + cc) * 16 + cq * 4 + (r & 3);
            t_lds[pos] = f2bf(vv[e]);
        }
    }
    __syncthreads();
    const uint4* src = (const uint4*)&t_lds[t * 16];
    uint4* dst = (uint4*)(Abf + (size_t)blockIdx.x * 4096 + t * 16);
    dst[0] = src[0];
    dst[1] = src[1];
}

// ---------------- prep: F0 -> Yhi/Ylo, FtB(bf16 blocked transpose), squ ----------------
__global__ __launch_bounds__(256) void k_prep(const float* __restrict__ F,
    const float* __restrict__ u, unsigned short* __restrict__ Yhi,
    unsigned short* __restrict__ Ylo, unsigned short* __restrict__ FtB,
    float2* __restrict__ squ)
{
    const int lane = threadIdx.x & 63;
    const int row  = blockIdx.x * 4 + (threadIdx.x >> 6);
    const float ui = u[row];
    const float f  = F[(size_t)row * CD + lane];
    const float yv = f * ui;
    const unsigned short h = f2bf(yv);
    Yhi[(size_t)row * CD + lane] = h;
    Ylo[(size_t)row * CD + lane] = f2bf(yv - bf2f(h));
    FtB[(size_t)(row >> 6) * (CD * 64) + (size_t)lane * 64 + (row & 63)] = f2bf(f);
    float s2 = yv * yv;
    #pragma unroll
    for (int o = 32; o > 0; o >>= 1) s2 += __shfl_xor(s2, o, 64);
    if (lane == 0) squ[row] = make_float2(s2, 0.5f * ui);
}

// ---------------- fused MFMA flash pass ----------------
// grid (64, 32): 64 i-rows per block, j-range js*128..+128 (JT_PER=2 tiles of 64).
// 4 waves, each a 16-row i-strip. Gram 6 mfma/ct (hi/lo), SCAD in regs,
// w -> per-wave LDS (pitch 72), PV 8 mfma. No barriers.
template<bool ABF>
__global__ __launch_bounds__(256, 8) void k_fused(
    const float* __restrict__ A, const unsigned short* __restrict__ Abf,
    const unsigned short* __restrict__ Yhi, const unsigned short* __restrict__ Ylo,
    const unsigned short* __restrict__ FtB, const float2* __restrict__ squ,
    const float* __restrict__ log_lams, const int k,
    float* __restrict__ partF, float* __restrict__ partQ)
{
    __shared__ __align__(16) unsigned short w_lds[4][16][72];
    const int tid = threadIdx.x, lane = tid & 63, wid = tid >> 6;
    const int m = lane & 15, b = lane >> 4;
    const int I0 = blockIdx.x * 64, js = blockIdx.y;

    const float lam   = __expf(log_lams[k]);
    const float invA1 = 1.0f / (SCAD_Af - 1.0f);
    const float c1    = SCAD_Af * lam * invA1;

    // Yi A-fragments
    const size_t ribase = (size_t)(I0 + 16*wid + m) * CD + 8*b;
    const bf16x8 yiH0 = *(const bf16x8*)(Yhi + ribase);
    const bf16x8 yiH1 = *(const bf16x8*)(Yhi + ribase + 32);
    const bf16x8 yiL0 = *(const bf16x8*)(Ylo + ribase);
    const bf16x8 yiL1 = *(const bf16x8*)(Ylo + ribase + 32);

    float sqi_r[4];
    #pragma unroll
    for (int reg = 0; reg < 4; ++reg)
        sqi_r[reg] = squ[I0 + 16*wid + 4*b + reg].x;

    f32x4 FV[4];
    #pragma unroll
    for (int ct = 0; ct < 4; ++ct) FV[ct] = (f32x4){0.f, 0.f, 0.f, 0.f};
    float qa[4] = {0.f, 0.f, 0.f, 0.f};

    // A-tile fragment base (permuted layout): lane-contiguous 32B
    const size_t afrag_off = (size_t)(64*wid + 16*b + m) * 16;
    bf16x8 aC0, aC1, aN0, aN1;
    if constexpr (ABF) {
        const size_t tb = ((size_t)blockIdx.x * 64 + (size_t)(js * JT_PER)) * 4096 + afrag_off;
        aC0 = *(const bf16x8*)(Abf + tb);
        aC1 = *(const bf16x8*)(Abf + tb + 8);
    }

    for (int jt = 0; jt < JT_PER; ++jt) {
        const int J0 = js * (64 * JT_PER) + jt * 64;

        if constexpr (ABF) {
            if (jt + 1 < JT_PER) {     // prefetch next A tile fragment
                const size_t tb = ((size_t)blockIdx.x * 64 + (size_t)(js * JT_PER + jt + 1)) * 4096 + afrag_off;
                aN0 = *(const bf16x8*)(Abf + tb);
                aN1 = *(const bf16x8*)(Abf + tb + 8);
            }
        }

        float sqj[4], ujh[4];
        #pragma unroll
        for (int ct = 0; ct < 4; ++ct) {
            const float2 s = squ[J0 + 16*ct + m];
            sqj[ct] = s.x; ujh[ct] = s.y;
        }

        // Gram: G[i][j] = Yi . Yj (hi/lo split, lo*lo dropped)
        f32x4 g[4];
        #pragma unroll
        for (int ct = 0; ct < 4; ++ct) {
            const size_t rb = (size_t)(J0 + 16*ct + m) * CD + 8*b;
            const bf16x8 bh0 = *(const bf16x8*)(Yhi + rb);
            const bf16x8 bh1 = *(const bf16x8*)(Yhi + rb + 32);
            const bf16x8 bl0 = *(const bf16x8*)(Ylo + rb);
            const bf16x8 bl1 = *(const bf16x8*)(Ylo + rb + 32);
            f32x4 acc = (f32x4){0.f, 0.f, 0.f, 0.f};
            acc = MFMA16(yiH0, bh0, acc);
            acc = MFMA16(yiH1, bh1, acc);
            acc = MFMA16(yiH0, bl0, acc);
            acc = MFMA16(yiH1, bl1, acc);
            acc = MFMA16(yiL0, bh0, acc);
            acc = MFMA16(yiL1, bh1, acc);
            g[ct] = acc;
        }

        // A values for this tile
        float av[4][4];
        if constexpr (ABF) {
            #pragma unroll
            for (int reg = 0; reg < 4; ++reg) {
                av[reg][0] = bf2f((unsigned short)aC0[reg]);
                av[reg][1] = bf2f((unsigned short)aC0[4 + reg]);
                av[reg][2] = bf2f((unsigned short)aC1[reg]);
                av[reg][3] = bf2f((unsigned short)aC1[4 + reg]);
            }
        } else {
            #pragma unroll
            for (int reg = 0; reg < 4; ++reg) {
                const size_t arb = (size_t)(I0 + 16*wid + 4*b + reg) * NN + J0 + m;
                #pragma unroll
                for (int ct = 0; ct < 4; ++ct)
                    av[reg][ct] = A[arb + 16*ct];
            }
        }

        const bool diag = (J0 == I0);

        // SCAD weight + q accumulation + w -> LDS (bf16)
        #pragma unroll
        for (int ct = 0; ct < 4; ++ct) {
            #pragma unroll
            for (int reg = 0; reg < 4; ++reg) {
                const float Z   = fmaf(-2.0f, g[ct][reg], sqi_r[reg] + sqj[ct]);
                const float Zp  = fmaxf(Z, 0.0f) + DIST_EPSf;
                const float rsq = __builtin_amdgcn_rsqf(Zp);
                const float y   = Zp * rsq;                         // sqrt(Zp)
                const float t1  = fmaf(-invA1, y, c1);              // (a*lam-y)/(a-1)
                const float rho = __builtin_amdgcn_fmed3f(t1, 0.0f, lam);
                const float wv  = fminf(rho * rsq, 2.0f);           // 2*min(rho/(2y),1)
                float aij = av[reg][ct];
                if (diag && ct == wid && m == 4*b + reg) aij += 1.0f;
                const float t = wv * aij * ujh[ct];                 // w*(A+I)*u_j
                qa[reg] += t;
                w_lds[wid][4*b + reg][m + 16*ct] = f2bf(t);
            }
        }

        // PV: FV[i][c] += w[i][j] * F[j][c]
        const size_t fb = (size_t)(J0 >> 6) * (CD * 64);
        #pragma unroll
        for (int ks = 0; ks < 2; ++ks) {
            const bf16x8 wf = *(const bf16x8*)&w_lds[wid][m][8*b + 32*ks];
            #pragma unroll
            for (int ct = 0; ct < 4; ++ct) {
                const bf16x8 ff = *(const bf16x8*)(FtB + fb +
                                     (size_t)(m + 16*ct) * 64 + 8*b + 32*ks);
                FV[ct] = MFMA16(wf, ff, FV[ct]);
            }
        }

        if constexpr (ABF) { aC0 = aN0; aC1 = aN1; }
    }

    // write partials
    const size_t base = (size_t)js * NN + I0 + 16*wid;
    #pragma unroll
    for (int ct = 0; ct < 4; ++ct)
        #pragma unroll
        for (int reg = 0; reg < 4; ++reg)
            partF[(base + 4*b + reg) * CD + m + 16*ct] = FV[ct][reg];

    #pragma unroll
    for (int reg = 0; reg < 4; ++reg) {
        float q = qa[reg];
        q += __shfl_xor(q, 1, 64);
        q += __shfl_xor(q, 2, 64);
        q += __shfl_xor(q, 4, 64);
        q += __shfl_xor(q, 8, 64);
        if (m == 0) partQ[base + 4*b + reg] = q;
    }
}

// ---------------- combine partials -> F_new, prep next-iter bf16 buffers ----------------
__global__ __launch_bounds__(256) void k_combine(
    const float* __restrict__ partF, const float* __restrict__ partQ,
    const float* __restrict__ F0, const float* __restrict__ lam_node,
    const float* __restrict__ u, float* __restrict__ Fout,
    unsigned short* __restrict__ Yhi, unsigned short* __restrict__ Ylo,
    unsigned short* __restrict__ FtB, float2* __restrict__ squ)
{
    const int lane = threadIdx.x & 63;
    const int row  = blockIdx.x * 4 + (threadIdx.x >> 6);
    float acc = 0.0f, q = 0.0f;
    #pragma unroll
    for (int s = 0; s < NSPLIT; ++s) {
        acc += partF[((size_t)s * NN + row) * CD + lane];
        q   += partQ[(size_t)s * NN + row];
    }
    const float ui = u[row];
    const float ln = lam_node[row];
    const float f0 = F0[(size_t)row * CD + lane];
    const float fn = (acc * ui + ln * f0) / (q * ui + ln);
    Fout[(size_t)row * CD + lane] = fn;
    const float yv = fn * ui;
    const unsigned short h = f2bf(yv);
    Yhi[(size_t)row * CD + lane] = h;
    Ylo[(size_t)row * CD + lane] = f2bf(yv - bf2f(h));
    FtB[(size_t)(row >> 6) * (CD * 64) + (size_t)lane * 64 + (row & 63)] = f2bf(fn);
    float s2 = yv * yv;
    #pragma unroll
    for (int o = 32; o > 0; o >>= 1) s2 += __shfl_xor(s2, o, 64);
    if (lane == 0) squ[row] = make_float2(s2, 0.5f * ui);
}

extern "C" void kernel_launch(void* const* d_in, const int* in_sizes, int n_in,
                              void* d_out, int out_size, void* d_ws, size_t ws_size,
                              hipStream_t stream)
{
    const float* A         = (const float*)d_in[0];
    const float* X         = (const float*)d_in[1];
    const float* W1        = (const float*)d_in[2];
    const float* b1        = (const float*)d_in[3];
    const float* W2        = (const float*)d_in[4];
    const float* b2        = (const float*)d_in[5];
    const float* log_lams  = (const float*)d_in[6];
    const float* raw_alpha = (const float*)d_in[7];
    float* out = (float*)d_out;

    char* p = (char*)d_ws;
    auto alloc = [&](size_t bytes) -> char* {
        char* r = p;
        p += (bytes + 255) & ~(size_t)255;
        return r;
    };
    float* Hid      = (float*)alloc((size_t)NN * HID * 4);
    float* F0       = (float*)alloc((size_t)NN * CD * 4);
    float* raw_lam  = (float*)alloc((size_t)NN * 4);
    float* lam_node = (float*)alloc((size_t)NN * 4);
    float* uvec     = (float*)alloc((size_t)NN * 4);
    float2* squ     = (float2*)alloc((size_t)NN * 8);
    float* Fbuf     = (float*)alloc((size_t)NN * CD * 4);
    unsigned short* Yhi = (unsigned short*)alloc((size_t)NN * CD * 2);
    unsigned short* Ylo = (unsigned short*)alloc((size_t)NN * CD * 2);
    unsigned short* FtB = (unsigned short*)alloc((size_t)NN * CD * 2);
    float* partF    = (float*)alloc((size_t)NSPLIT * NN * CD * 4);
    float* partQ    = (float*)alloc((size_t)NSPLIT * NN * 4);
    const size_t base_used = (size_t)(p - (char*)d_ws);
    const size_t abf_bytes = (size_t)NN * NN * 2;
    const bool use_abf = (ws_size >= base_used + abf_bytes + 4096);
    unsigned short* Abf = use_abf ? (unsigned short*)alloc(abf_bytes) : (unsigned short*)nullptr;

    k_gemm1<<<dim3(64, 4), 256, 0, stream>>>(X, W1, b1, Hid);
    k_gemm2<<<dim3(64),    256, 0, stream>>>(Hid, W2, b2, F0);
    k_conf <<<dim3(1024),  256, 0, stream>>>(F0, raw_alpha, raw_lam);
    k_lam  <<<dim3(1),     256, 0, stream>>>(raw_lam, lam_node);
    k_deg  <<<dim3(4096),  256, 0, stream>>>(A, uvec);
    k_prep <<<dim3(1024),  256, 0, stream>>>(F0, uvec, Yhi, Ylo, FtB, squ);
    if (use_abf)
        k_castA<<<dim3(4096), 256, 0, stream>>>(A, Abf);

    for (int k = 0; k < 10; ++k) {
        float* Fout = (k == 9) ? out : Fbuf;
        if (use_abf)
            k_fused<true><<<dim3(64, NSPLIT), 256, 0, stream>>>(A, Abf, Yhi, Ylo, FtB,
                squ, log_lams, k, partF, partQ);
        else
            k_fused<false><<<dim3(64, NSPLIT), 256, 0, stream>>>(A, Abf, Yhi, Ylo, FtB,
                squ, log_lams, k, partF, partQ);
        k_combine<<<dim3(1024), 256, 0, stream>>>(partF, partQ, F0, lam_node, uvec,
                                                  Fout, Yhi, Ylo, FtB, squ);
    }
}

// Round 7
// 827.371 us; speedup vs baseline: 1.4942x; 1.4942x over previous
//
#include <hip/hip_runtime.h>
#include <math.h>

// RUNG confidence-lambda QN-IRLS, round 6 (resubmit): r5 occupancy with r4 registers.
// NSPLIT=32 (2048 blocks = 8 blocks/CU), launch_bounds(256,4) -> VGPR=64, no spills.

#define NN 4096
#define DIN 512
#define HID 256
#define CD 64
#define NSPLIT 32
#define JT_PER 2   // (NN/NSPLIT)/64

static constexpr float SCAD_Af   = 3.7f;
static constexpr float EPSf      = 1e-6f;
static constexpr float DIST_EPSf = 1e-8f;
#define LAM_BASEF ((float)(1.0 / 0.9 - 1.0))

typedef __attribute__((ext_vector_type(8))) short bf16x8;
typedef __attribute__((ext_vector_type(4))) float f32x4;

#define MFMA16(a, b, c) __builtin_amdgcn_mfma_f32_16x16x32_bf16((a), (b), (c), 0, 0, 0)

__device__ inline unsigned short f2bf(float f) {
    unsigned u = __float_as_uint(f);
    u += 0x7FFFu + ((u >> 16) & 1u);          // RNE
    return (unsigned short)(u >> 16);
}
__device__ inline float bf2f(unsigned short h) {
    return __uint_as_float(((unsigned)h) << 16);
}

// ---------------- GEMM1: Hid = relu(X @ W1 + b1) ----------------
__global__ __launch_bounds__(256) void k_gemm1(const float* __restrict__ X,
    const float* __restrict__ W1, const float* __restrict__ b1,
    float* __restrict__ Hid)
{
    __shared__ float Xs[16][68];
    __shared__ float Ws[16][68];
    const int tid = threadIdx.x;
    const int tx = tid & 15, ty = tid >> 4;
    const int M0 = blockIdx.x * 64, N0 = blockIdx.y * 64;
    float acc[4][4] = {};
    for (int k0 = 0; k0 < DIN; k0 += 16) {
        __syncthreads();
        {
            const int kk = tid & 15, mm = tid >> 4;
            #pragma unroll
            for (int r = 0; r < 4; ++r)
                Xs[kk][mm + 16*r] = X[(size_t)(M0 + mm + 16*r) * DIN + k0 + kk];
            const int n = tid & 63, kw = tid >> 6;
            #pragma unroll
            for (int r = 0; r < 4; ++r)
                Ws[kw + 4*r][n] = W1[(size_t)(k0 + kw + 4*r) * HID + N0 + n];
        }
        __syncthreads();
        #pragma unroll
        for (int kk = 0; kk < 16; ++kk) {
            const float4 av = *(const float4*)&Xs[kk][4*ty];
            const float4 bv = *(const float4*)&Ws[kk][4*tx];
            const float a[4] = {av.x, av.y, av.z, av.w};
            const float b[4] = {bv.x, bv.y, bv.z, bv.w};
            #pragma unroll
            for (int i = 0; i < 4; ++i)
                #pragma unroll
                for (int j = 0; j < 4; ++j)
                    acc[i][j] = fmaf(a[i], b[j], acc[i][j]);
        }
    }
    #pragma unroll
    for (int i = 0; i < 4; ++i)
        #pragma unroll
        for (int j = 0; j < 4; ++j) {
            const int gn = N0 + 4*tx + j;
            const float v = acc[i][j] + b1[gn];
            Hid[(size_t)(M0 + 4*ty + i) * HID + gn] = fmaxf(v, 0.0f);
        }
}

// ---------------- GEMM2: F0 = Hid @ W2 + b2 ----------------
__global__ __launch_bounds__(256) void k_gemm2(const float* __restrict__ Hd,
    const float* __restrict__ W2, const float* __restrict__ b2,
    float* __restrict__ F0)
{
    __shared__ float Hs[16][68];
    __shared__ float Ws[16][68];
    const int tid = threadIdx.x;
    const int tx = tid & 15, ty = tid >> 4;
    const int M0 = blockIdx.x * 64;
    float acc[4][4] = {};
    for (int k0 = 0; k0 < HID; k0 += 16) {
        __syncthreads();
        {
            const int kk = tid & 15, mm = tid >> 4;
            #pragma unroll
            for (int r = 0; r < 4; ++r)
                Hs[kk][mm + 16*r] = Hd[(size_t)(M0 + mm + 16*r) * HID + k0 + kk];
            const int n = tid & 63, kw = tid >> 6;
            #pragma unroll
            for (int r = 0; r < 4; ++r)
                Ws[kw + 4*r][n] = W2[(size_t)(k0 + kw + 4*r) * CD + n];
        }
        __syncthreads();
        #pragma unroll
        for (int kk = 0; kk < 16; ++kk) {
            const float4 av = *(const float4*)&Hs[kk][4*ty];
            const float4 bv = *(const float4*)&Ws[kk][4*tx];
            const float a[4] = {av.x, av.y, av.z, av.w};
            const float b[4] = {bv.x, bv.y, bv.z, bv.w};
            #pragma unroll
            for (int i = 0; i < 4; ++i)
                #pragma unroll
                for (int j = 0; j < 4; ++j)
                    acc[i][j] = fmaf(a[i], b[j], acc[i][j]);
        }
    }
    #pragma unroll
    for (int i = 0; i < 4; ++i)
        #pragma unroll
        for (int j = 0; j < 4; ++j) {
            const int gn = 4*tx + j;
            F0[(size_t)(M0 + 4*ty + i) * CD + gn] = acc[i][j] + b2[gn];
        }
}

// ---------------- conf -> raw_lam ----------------
__global__ __launch_bounds__(256) void k_conf(const float* __restrict__ F0,
    const float* __restrict__ raw_alpha, float* __restrict__ raw_lam)
{
    const int lane = threadIdx.x & 63;
    const int row  = blockIdx.x * 4 + (threadIdx.x >> 6);
    const float alpha = log1pf(expf(raw_alpha[0])) + 0.5f;
    const float f = F0[(size_t)row * CD + lane];
    float m = f;
    #pragma unroll
    for (int o = 32; o > 0; o >>= 1) m = fmaxf(m, __shfl_xor(m, o, 64));
    float e = expf(f - m);
    #pragma unroll
    for (int o = 32; o > 0; o >>= 1) e += __shfl_xor(e, o, 64);
    float conf = 1.0f / e;
    conf = fminf(fmaxf(conf, EPSf), 1.0f - EPSf);
    const float rl = LAM_BASEF * powf(fmaxf(1.0f - conf, EPSf), alpha);
    if (lane == 0) raw_lam[row] = rl;
}

// ---------------- lam_node ----------------
__global__ __launch_bounds__(256) void k_lam(const float* __restrict__ raw_lam,
    float* __restrict__ lam_node)
{
    __shared__ float red[256];
    float s = 0.0f;
    for (int i = threadIdx.x; i < NN; i += 256) s += raw_lam[i];
    red[threadIdx.x] = s;
    __syncthreads();
    for (int o = 128; o > 0; o >>= 1) {
        if (threadIdx.x < o) red[threadIdx.x] += red[threadIdx.x + o];
        __syncthreads();
    }
    const float mean  = red[0] * (1.0f / NN);
    const float scale = LAM_BASEF / fmaxf(mean, EPSf);
    for (int i = threadIdx.x; i < NN; i += 256)
        lam_node[i] = fmaxf(raw_lam[i] * scale, EPSf);
}

// ---------------- deg -> u = 1/sqrt(rowsum(A)+1) ----------------
__global__ __launch_bounds__(256) void k_deg(const float* __restrict__ A,
    float* __restrict__ u)
{
    __shared__ float red[256];
    const int i = blockIdx.x;
    float s = 0.0f;
    for (int j = threadIdx.x; j < NN; j += 256) s += A[(size_t)i * NN + j];
    red[threadIdx.x] = s;
    __syncthreads();
    for (int o = 128; o > 0; o >>= 1) {
        if (threadIdx.x < o) red[threadIdx.x] += red[threadIdx.x + o];
        __syncthreads();
    }
    if (threadIdx.x == 0) u[i] = 1.0f / sqrtf(red[0] + 1.0f);
}

// ---------------- one-time A -> bf16 cast, permuted into MFMA C-fragment order ----
// tile (ti,tj) 64x64; element (r,c) -> pos = ((r>>2)*16 + (c&15))*16 + (c>>4)*4 + (r&3)
__global__ __launch_bounds__(256) void k_castA(const float* __restrict__ A,
    unsigned short* __restrict__ Abf)
{
    __shared__ unsigned short t_lds[4096];
    const int ti = blockIdx.x >> 6, tj = blockIdx.x & 63;
    const int t = threadIdx.x;
    const int r = t >> 2, cq = t & 3;
    const size_t arow = (size_t)(ti * 64 + r) * NN + tj * 64 + cq * 16;
    #pragma unroll
    for (int q = 0; q < 4; ++q) {
        const float4 v = *(const float4*)(A + arow + 4 * q);
        const float vv[4] = {v.x, v.y, v.z, v.w};
        #pragma unroll
        for (int e = 0; e < 4; ++e) {
            const int cc = 4 * q + e;                       // c & 15
            const int pos = ((r >> 2) * 16 + cc) * 16 + cq * 4 + (r & 3);
            t_lds[pos] = f2bf(vv[e]);
        }
    }
    __syncthreads();
    const uint4* src = (const uint4*)&t_lds[t * 16];
    uint4* dst = (uint4*)(Abf + (size_t)blockIdx.x * 4096 + t * 16);
    dst[0] = src[0];
    dst[1] = src[1];
}

// ---------------- prep: F0 -> Yhi/Ylo, FtB(bf16 blocked transpose), squ ----------------
__global__ __launch_bounds__(256) void k_prep(const float* __restrict__ F,
    const float* __restrict__ u, unsigned short* __restrict__ Yhi,
    unsigned short* __restrict__ Ylo, unsigned short* __restrict__ FtB,
    float2* __restrict__ squ)
{
    const int lane = threadIdx.x & 63;
    const int row  = blockIdx.x * 4 + (threadIdx.x >> 6);
    const float ui = u[row];
    const float f  = F[(size_t)row * CD + lane];
    const float yv = f * ui;
    const unsigned short h = f2bf(yv);
    Yhi[(size_t)row * CD + lane] = h;
    Ylo[(size_t)row * CD + lane] = f2bf(yv - bf2f(h));
    FtB[(size_t)(row >> 6) * (CD * 64) + (size_t)lane * 64 + (row & 63)] = f2bf(f);
    float s2 = yv * yv;
    #pragma unroll
    for (int o = 32; o > 0; o >>= 1) s2 += __shfl_xor(s2, o, 64);
    if (lane == 0) squ[row] = make_float2(s2, 0.5f * ui);
}

// ---------------- fused MFMA flash pass ----------------
// grid (64, 32): 64 i-rows per block, j-range js*128..+128 (JT_PER=2 tiles of 64).
// 4 waves, each a 16-row i-strip. Gram 6 mfma/ct (hi/lo), SCAD in regs,
// w -> per-wave LDS (pitch 72), PV 8 mfma. No barriers.
template<bool ABF>
__global__ __launch_bounds__(256, 4) void k_fused(
    const float* __restrict__ A, const unsigned short* __restrict__ Abf,
    const unsigned short* __restrict__ Yhi, const unsigned short* __restrict__ Ylo,
    const unsigned short* __restrict__ FtB, const float2* __restrict__ squ,
    const float* __restrict__ log_lams, const int k,
    float* __restrict__ partF, float* __restrict__ partQ)
{
    __shared__ __align__(16) unsigned short w_lds[4][16][72];
    const int tid = threadIdx.x, lane = tid & 63, wid = tid >> 6;
    const int m = lane & 15, b = lane >> 4;
    const int I0 = blockIdx.x * 64, js = blockIdx.y;

    const float lam   = __expf(log_lams[k]);
    const float invA1 = 1.0f / (SCAD_Af - 1.0f);
    const float c1    = SCAD_Af * lam * invA1;

    // Yi A-fragments
    const size_t ribase = (size_t)(I0 + 16*wid + m) * CD + 8*b;
    const bf16x8 yiH0 = *(const bf16x8*)(Yhi + ribase);
    const bf16x8 yiH1 = *(const bf16x8*)(Yhi + ribase + 32);
    const bf16x8 yiL0 = *(const bf16x8*)(Ylo + ribase);
    const bf16x8 yiL1 = *(const bf16x8*)(Ylo + ribase + 32);

    float sqi_r[4];
    #pragma unroll
    for (int reg = 0; reg < 4; ++reg)
        sqi_r[reg] = squ[I0 + 16*wid + 4*b + reg].x;

    f32x4 FV[4];
    #pragma unroll
    for (int ct = 0; ct < 4; ++ct) FV[ct] = (f32x4){0.f, 0.f, 0.f, 0.f};
    float qa[4] = {0.f, 0.f, 0.f, 0.f};

    // A-tile fragment base (permuted layout): lane-contiguous 32B
    const size_t afrag_off = (size_t)(64*wid + 16*b + m) * 16;
    bf16x8 aC0, aC1, aN0, aN1;
    if constexpr (ABF) {
        const size_t tb = ((size_t)blockIdx.x * 64 + (size_t)(js * JT_PER)) * 4096 + afrag_off;
        aC0 = *(const bf16x8*)(Abf + tb);
        aC1 = *(const bf16x8*)(Abf + tb + 8);
    }

    for (int jt = 0; jt < JT_PER; ++jt) {
        const int J0 = js * (64 * JT_PER) + jt * 64;

        if constexpr (ABF) {
            if (jt + 1 < JT_PER) {     // prefetch next A tile fragment
                const size_t tb = ((size_t)blockIdx.x * 64 + (size_t)(js * JT_PER + jt + 1)) * 4096 + afrag_off;
                aN0 = *(const bf16x8*)(Abf + tb);
                aN1 = *(const bf16x8*)(Abf + tb + 8);
            }
        }

        float sqj[4], ujh[4];
        #pragma unroll
        for (int ct = 0; ct < 4; ++ct) {
            const float2 s = squ[J0 + 16*ct + m];
            sqj[ct] = s.x; ujh[ct] = s.y;
        }

        // Gram: G[i][j] = Yi . Yj (hi/lo split, lo*lo dropped)
        f32x4 g[4];
        #pragma unroll
        for (int ct = 0; ct < 4; ++ct) {
            const size_t rb = (size_t)(J0 + 16*ct + m) * CD + 8*b;
            const bf16x8 bh0 = *(const bf16x8*)(Yhi + rb);
            const bf16x8 bh1 = *(const bf16x8*)(Yhi + rb + 32);
            const bf16x8 bl0 = *(const bf16x8*)(Ylo + rb);
            const bf16x8 bl1 = *(const bf16x8*)(Ylo + rb + 32);
            f32x4 acc = (f32x4){0.f, 0.f, 0.f, 0.f};
            acc = MFMA16(yiH0, bh0, acc);
            acc = MFMA16(yiH1, bh1, acc);
            acc = MFMA16(yiH0, bl0, acc);
            acc = MFMA16(yiH1, bl1, acc);
            acc = MFMA16(yiL0, bh0, acc);
            acc = MFMA16(yiL1, bh1, acc);
            g[ct] = acc;
        }

        // A values for this tile
        float av[4][4];
        if constexpr (ABF) {
            #pragma unroll
            for (int reg = 0; reg < 4; ++reg) {
                av[reg][0] = bf2f((unsigned short)aC0[reg]);
                av[reg][1] = bf2f((unsigned short)aC0[4 + reg]);
                av[reg][2] = bf2f((unsigned short)aC1[reg]);
                av[reg][3] = bf2f((unsigned short)aC1[4 + reg]);
            }
        } else {
            #pragma unroll
            for (int reg = 0; reg < 4; ++reg) {
                const size_t arb = (size_t)(I0 + 16*wid + 4*b + reg) * NN + J0 + m;
                #pragma unroll
                for (int ct = 0; ct < 4; ++ct)
                    av[reg][ct] = A[arb + 16*ct];
            }
        }

        const bool diag = (J0 == I0);

        // SCAD weight + q accumulation + w -> LDS (bf16)
        #pragma unroll
        for (int ct = 0; ct < 4; ++ct) {
            #pragma unroll
            for (int reg = 0; reg < 4; ++reg) {
                const float Z   = fmaf(-2.0f, g[ct][reg], sqi_r[reg] + sqj[ct]);
                const float Zp  = fmaxf(Z, 0.0f) + DIST_EPSf;
                const float rsq = __builtin_amdgcn_rsqf(Zp);
                const float y   = Zp * rsq;                         // sqrt(Zp)
                const float t1  = fmaf(-invA1, y, c1);              // (a*lam-y)/(a-1)
                const float rho = __builtin_amdgcn_fmed3f(t1, 0.0f, lam);
                const float wv  = fminf(rho * rsq, 2.0f);           // 2*min(rho/(2y),1)
                float aij = av[reg][ct];
                if (diag && ct == wid && m == 4*b + reg) aij += 1.0f;
                const float t = wv * aij * ujh[ct];                 // w*(A+I)*u_j
                qa[reg] += t;
                w_lds[wid][4*b + reg][m + 16*ct] = f2bf(t);
            }
        }

        // PV: FV[i][c] += w[i][j] * F[j][c]
        const size_t fb = (size_t)(J0 >> 6) * (CD * 64);
        #pragma unroll
        for (int ks = 0; ks < 2; ++ks) {
            const bf16x8 wf = *(const bf16x8*)&w_lds[wid][m][8*b + 32*ks];
            #pragma unroll
            for (int ct = 0; ct < 4; ++ct) {
                const bf16x8 ff = *(const bf16x8*)(FtB + fb +
                                     (size_t)(m + 16*ct) * 64 + 8*b + 32*ks);
                FV[ct] = MFMA16(wf, ff, FV[ct]);
            }
        }

        if constexpr (ABF) { aC0 = aN0; aC1 = aN1; }
    }

    // write partials
    const size_t base = (size_t)js * NN + I0 + 16*wid;
    #pragma unroll
    for (int ct = 0; ct < 4; ++ct)
        #pragma unroll
        for (int reg = 0; reg < 4; ++reg)
            partF[(base + 4*b + reg) * CD + m + 16*ct] = FV[ct][reg];

    #pragma unroll
    for (int reg = 0; reg < 4; ++reg) {
        float q = qa[reg];
        q += __shfl_xor(q, 1, 64);
        q += __shfl_xor(q, 2, 64);
        q += __shfl_xor(q, 4, 64);
        q += __shfl_xor(q, 8, 64);
        if (m == 0) partQ[base + 4*b + reg] = q;
    }
}

// ---------------- combine partials -> F_new, prep next-iter bf16 buffers ----------------
__global__ __launch_bounds__(256) void k_combine(
    const float* __restrict__ partF, const float* __restrict__ partQ,
    const float* __restrict__ F0, const float* __restrict__ lam_node,
    const float* __restrict__ u, float* __restrict__ Fout,
    unsigned short* __restrict__ Yhi, unsigned short* __restrict__ Ylo,
    unsigned short* __restrict__ FtB, float2* __restrict__ squ)
{
    const int lane = threadIdx.x & 63;
    const int row  = blockIdx.x * 4 + (threadIdx.x >> 6);
    float acc = 0.0f, q = 0.0f;
    #pragma unroll
    for (int s = 0; s < NSPLIT; ++s) {
        acc += partF[((size_t)s * NN + row) * CD + lane];
        q   += partQ[(size_t)s * NN + row];
    }
    const float ui = u[row];
    const float ln = lam_node[row];
    const float f0 = F0[(size_t)row * CD + lane];
    const float fn = (acc * ui + ln * f0) / (q * ui + ln);
    Fout[(size_t)row * CD + lane] = fn;
    const float yv = fn * ui;
    const unsigned short h = f2bf(yv);
    Yhi[(size_t)row * CD + lane] = h;
    Ylo[(size_t)row * CD + lane] = f2bf(yv - bf2f(h));
    FtB[(size_t)(row >> 6) * (CD * 64) + (size_t)lane * 64 + (row & 63)] = f2bf(fn);
    float s2 = yv * yv;
    #pragma unroll
    for (int o = 32; o > 0; o >>= 1) s2 += __shfl_xor(s2, o, 64);
    if (lane == 0) squ[row] = make_float2(s2, 0.5f * ui);
}

extern "C" void kernel_launch(void* const* d_in, const int* in_sizes, int n_in,
                              void* d_out, int out_size, void* d_ws, size_t ws_size,
                              hipStream_t stream)
{
    const float* A         = (const float*)d_in[0];
    const float* X         = (const float*)d_in[1];
    const float* W1        = (const float*)d_in[2];
    const float* b1        = (const float*)d_in[3];
    const float* W2        = (const float*)d_in[4];
    const float* b2        = (const float*)d_in[5];
    const float* log_lams  = (const float*)d_in[6];
    const float* raw_alpha = (const float*)d_in[7];
    float* out = (float*)d_out;

    char* p = (char*)d_ws;
    auto alloc = [&](size_t bytes) -> char* {
        char* r = p;
        p += (bytes + 255) & ~(size_t)255;
        return r;
    };
    float* Hid      = (float*)alloc((size_t)NN * HID * 4);
    float* F0       = (float*)alloc((size_t)NN * CD * 4);
    float* raw_lam  = (float*)alloc((size_t)NN * 4);
    float* lam_node = (float*)alloc((size_t)NN * 4);
    float* uvec     = (float*)alloc((size_t)NN * 4);
    float2* squ     = (float2*)alloc((size_t)NN * 8);
    float* Fbuf     = (float*)alloc((size_t)NN * CD * 4);
    unsigned short* Yhi = (unsigned short*)alloc((size_t)NN * CD * 2);
    unsigned short* Ylo = (unsigned short*)alloc((size_t)NN * CD * 2);
    unsigned short* FtB = (unsigned short*)alloc((size_t)NN * CD * 2);
    float* partF    = (float*)alloc((size_t)NSPLIT * NN * CD * 4);
    float* partQ    = (float*)alloc((size_t)NSPLIT * NN * 4);
    const size_t base_used = (size_t)(p - (char*)d_ws);
    const size_t abf_bytes = (size_t)NN * NN * 2;
    const bool use_abf = (ws_size >= base_used + abf_bytes + 4096);
    unsigned short* Abf = use_abf ? (unsigned short*)alloc(abf_bytes) : (unsigned short*)nullptr;

    k_gemm1<<<dim3(64, 4), 256, 0, stream>>>(X, W1, b1, Hid);
    k_gemm2<<<dim3(64),    256, 0, stream>>>(Hid, W2, b2, F0);
    k_conf <<<dim3(1024),  256, 0, stream>>>(F0, raw_alpha, raw_lam);
    k_lam  <<<dim3(1),     256, 0, stream>>>(raw_lam, lam_node);
    k_deg  <<<dim3(4096),  256, 0, stream>>>(A, uvec);
    k_prep <<<dim3(1024),  256, 0, stream>>>(F0, uvec, Yhi, Ylo, FtB, squ);
    if (use_abf)
        k_castA<<<dim3(4096), 256, 0, stream>>>(A, Abf);

    for (int k = 0; k < 10; ++k) {
        float* Fout = (k == 9) ? out : Fbuf;
        if (use_abf)
            k_fused<true><<<dim3(64, NSPLIT), 256, 0, stream>>>(A, Abf, Yhi, Ylo, FtB,
                squ, log_lams, k, partF, partQ);
        else
            k_fused<false><<<dim3(64, NSPLIT), 256, 0, stream>>>(A, Abf, Yhi, Ylo, FtB,
                squ, log_lams, k, partF, partQ);
        k_combine<<<dim3(1024), 256, 0, stream>>>(partF, partQ, F0, lam_node, uvec,
                                                  Fout, Yhi, Ylo, FtB, squ);
    }
}

// Round 8
// 551.022 us; speedup vs baseline: 2.2436x; 1.5015x over previous
//
#include <hip/hip_runtime.h>
#include <math.h>

// RUNG confidence-lambda QN-IRLS, round 8: fragment-contiguous global layouts.
// Yhi/Ylo/F stored in MFMA-fragment order (1KB contiguous per wave load) to kill
// the 16-txn/instruction scatter that serialized the TA in r7. Same math as r7.

#define NN 4096
#define DIN 512
#define HID 256
#define CD 64
#define NSPLIT 32
#define JT_PER 2   // (NN/NSPLIT)/64

static constexpr float SCAD_Af   = 3.7f;
static constexpr float EPSf      = 1e-6f;
static constexpr float DIST_EPSf = 1e-8f;
#define LAM_BASEF ((float)(1.0 / 0.9 - 1.0))

typedef __attribute__((ext_vector_type(8))) short bf16x8;
typedef __attribute__((ext_vector_type(4))) float f32x4;

#define MFMA16(a, b, c) __builtin_amdgcn_mfma_f32_16x16x32_bf16((a), (b), (c), 0, 0, 0)

__device__ inline unsigned short f2bf(float f) {
    unsigned u = __float_as_uint(f);
    u += 0x7FFFu + ((u >> 16) & 1u);          // RNE
    return (unsigned short)(u >> 16);
}
__device__ inline float bf2f(unsigned short h) {
    return __uint_as_float(((unsigned)h) << 16);
}

// Permuted Y layout: Yp[(tile*8 + ct*2 + h)*512 + (b*16+m)*8 + e]
//   = Y[tile*64 + ct*16 + m][h*32 + b*8 + e]
// (fused reads: lane=(b*16+m) -> contiguous 16B/lane, 1KB/wave-instruction)
__device__ inline int yperm_off(int row, int c) {
    const int tile = row >> 6, ct = (row >> 4) & 3, m = row & 15;
    return (tile * 8 + ct * 2 + (c >> 5)) * 512 + ((c >> 3) & 3) * 128 + m * 8 + (c & 7);
}
// Permuted F layout: Fp[(tile*8 + ct*2 + ks)*512 + (b*16+m)*8 + e]
//   = F[tile*64 + 32*ks + 8*b + e][16*ct + m]   (PV B-fragment order)
__device__ inline int fperm_off(int row, int c) {
    const int tile = row >> 6;
    return (tile * 8 + (c >> 4) * 2 + ((row >> 5) & 1)) * 512
         + (((row >> 3) & 3) * 16 + (c & 15)) * 8 + (row & 7);
}

// ---------------- GEMM1: Hid = relu(X @ W1 + b1) ----------------
__global__ __launch_bounds__(256) void k_gemm1(const float* __restrict__ X,
    const float* __restrict__ W1, const float* __restrict__ b1,
    float* __restrict__ Hid)
{
    __shared__ float Xs[16][68];
    __shared__ float Ws[16][68];
    const int tid = threadIdx.x;
    const int tx = tid & 15, ty = tid >> 4;
    const int M0 = blockIdx.x * 64, N0 = blockIdx.y * 64;
    float acc[4][4] = {};
    for (int k0 = 0; k0 < DIN; k0 += 16) {
        __syncthreads();
        {
            const int kk = tid & 15, mm = tid >> 4;
            #pragma unroll
            for (int r = 0; r < 4; ++r)
                Xs[kk][mm + 16*r] = X[(size_t)(M0 + mm + 16*r) * DIN + k0 + kk];
            const int n = tid & 63, kw = tid >> 6;
            #pragma unroll
            for (int r = 0; r < 4; ++r)
                Ws[kw + 4*r][n] = W1[(size_t)(k0 + kw + 4*r) * HID + N0 + n];
        }
        __syncthreads();
        #pragma unroll
        for (int kk = 0; kk < 16; ++kk) {
            const float4 av = *(const float4*)&Xs[kk][4*ty];
            const float4 bv = *(const float4*)&Ws[kk][4*tx];
            const float a[4] = {av.x, av.y, av.z, av.w};
            const float b[4] = {bv.x, bv.y, bv.z, bv.w};
            #pragma unroll
            for (int i = 0; i < 4; ++i)
                #pragma unroll
                for (int j = 0; j < 4; ++j)
                    acc[i][j] = fmaf(a[i], b[j], acc[i][j]);
        }
    }
    #pragma unroll
    for (int i = 0; i < 4; ++i)
        #pragma unroll
        for (int j = 0; j < 4; ++j) {
            const int gn = N0 + 4*tx + j;
            const float v = acc[i][j] + b1[gn];
            Hid[(size_t)(M0 + 4*ty + i) * HID + gn] = fmaxf(v, 0.0f);
        }
}

// ---------------- GEMM2: F0 = Hid @ W2 + b2 ----------------
__global__ __launch_bounds__(256) void k_gemm2(const float* __restrict__ Hd,
    const float* __restrict__ W2, const float* __restrict__ b2,
    float* __restrict__ F0)
{
    __shared__ float Hs[16][68];
    __shared__ float Ws[16][68];
    const int tid = threadIdx.x;
    const int tx = tid & 15, ty = tid >> 4;
    const int M0 = blockIdx.x * 64;
    float acc[4][4] = {};
    for (int k0 = 0; k0 < HID; k0 += 16) {
        __syncthreads();
        {
            const int kk = tid & 15, mm = tid >> 4;
            #pragma unroll
            for (int r = 0; r < 4; ++r)
                Hs[kk][mm + 16*r] = Hd[(size_t)(M0 + mm + 16*r) * HID + k0 + kk];
            const int n = tid & 63, kw = tid >> 6;
            #pragma unroll
            for (int r = 0; r < 4; ++r)
                Ws[kw + 4*r][n] = W2[(size_t)(k0 + kw + 4*r) * CD + n];
        }
        __syncthreads();
        #pragma unroll
        for (int kk = 0; kk < 16; ++kk) {
            const float4 av = *(const float4*)&Hs[kk][4*ty];
            const float4 bv = *(const float4*)&Ws[kk][4*tx];
            const float a[4] = {av.x, av.y, av.z, av.w};
            const float b[4] = {bv.x, bv.y, bv.z, bv.w};
            #pragma unroll
            for (int i = 0; i < 4; ++i)
                #pragma unroll
                for (int j = 0; j < 4; ++j)
                    acc[i][j] = fmaf(a[i], b[j], acc[i][j]);
        }
    }
    #pragma unroll
    for (int i = 0; i < 4; ++i)
        #pragma unroll
        for (int j = 0; j < 4; ++j) {
            const int gn = 4*tx + j;
            F0[(size_t)(M0 + 4*ty + i) * CD + gn] = acc[i][j] + b2[gn];
        }
}

// ---------------- conf -> raw_lam ----------------
__global__ __launch_bounds__(256) void k_conf(const float* __restrict__ F0,
    const float* __restrict__ raw_alpha, float* __restrict__ raw_lam)
{
    const int lane = threadIdx.x & 63;
    const int row  = blockIdx.x * 4 + (threadIdx.x >> 6);
    const float alpha = log1pf(expf(raw_alpha[0])) + 0.5f;
    const float f = F0[(size_t)row * CD + lane];
    float m = f;
    #pragma unroll
    for (int o = 32; o > 0; o >>= 1) m = fmaxf(m, __shfl_xor(m, o, 64));
    float e = expf(f - m);
    #pragma unroll
    for (int o = 32; o > 0; o >>= 1) e += __shfl_xor(e, o, 64);
    float conf = 1.0f / e;
    conf = fminf(fmaxf(conf, EPSf), 1.0f - EPSf);
    const float rl = LAM_BASEF * powf(fmaxf(1.0f - conf, EPSf), alpha);
    if (lane == 0) raw_lam[row] = rl;
}

// ---------------- lam_node ----------------
__global__ __launch_bounds__(256) void k_lam(const float* __restrict__ raw_lam,
    float* __restrict__ lam_node)
{
    __shared__ float red[256];
    float s = 0.0f;
    for (int i = threadIdx.x; i < NN; i += 256) s += raw_lam[i];
    red[threadIdx.x] = s;
    __syncthreads();
    for (int o = 128; o > 0; o >>= 1) {
        if (threadIdx.x < o) red[threadIdx.x] += red[threadIdx.x + o];
        __syncthreads();
    }
    const float mean  = red[0] * (1.0f / NN);
    const float scale = LAM_BASEF / fmaxf(mean, EPSf);
    for (int i = threadIdx.x; i < NN; i += 256)
        lam_node[i] = fmaxf(raw_lam[i] * scale, EPSf);
}

// ---------------- deg -> u = 1/sqrt(rowsum(A)+1) ----------------
__global__ __launch_bounds__(256) void k_deg(const float* __restrict__ A,
    float* __restrict__ u)
{
    __shared__ float red[256];
    const int i = blockIdx.x;
    float s = 0.0f;
    for (int j = threadIdx.x; j < NN; j += 256) s += A[(size_t)i * NN + j];
    red[threadIdx.x] = s;
    __syncthreads();
    for (int o = 128; o > 0; o >>= 1) {
        if (threadIdx.x < o) red[threadIdx.x] += red[threadIdx.x + o];
        __syncthreads();
    }
    if (threadIdx.x == 0) u[i] = 1.0f / sqrtf(red[0] + 1.0f);
}

// ---------------- one-time A -> bf16 cast, permuted into MFMA C-fragment order ----
__global__ __launch_bounds__(256) void k_castA(const float* __restrict__ A,
    unsigned short* __restrict__ Abf)
{
    __shared__ unsigned short t_lds[4096];
    const int ti = blockIdx.x >> 6, tj = blockIdx.x & 63;
    const int t = threadIdx.x;
    const int r = t >> 2, cq = t & 3;
    const size_t arow = (size_t)(ti * 64 + r) * NN + tj * 64 + cq * 16;
    #pragma unroll
    for (int q = 0; q < 4; ++q) {
        const float4 v = *(const float4*)(A + arow + 4 * q);
        const float vv[4] = {v.x, v.y, v.z, v.w};
        #pragma unroll
        for (int e = 0; e < 4; ++e) {
            const int cc = 4 * q + e;                       // c & 15
            const int pos = ((r >> 2) * 16 + cc) * 16 + cq * 4 + (r & 3);
            t_lds[pos] = f2bf(vv[e]);
        }
    }
    __syncthreads();
    const uint4* src = (const uint4*)&t_lds[t * 16];
    uint4* dst = (uint4*)(Abf + (size_t)blockIdx.x * 4096 + t * 16);
    dst[0] = src[0];
    dst[1] = src[1];
}

// ---------------- prep: F0 -> Yp(hi/lo), Fp (fragment layouts), squ ----------------
__global__ __launch_bounds__(256) void k_prep(const float* __restrict__ F,
    const float* __restrict__ u, unsigned short* __restrict__ Yph,
    unsigned short* __restrict__ Ypl, unsigned short* __restrict__ Fp,
    float2* __restrict__ squ)
{
    const int lane = threadIdx.x & 63;
    const int row  = blockIdx.x * 4 + (threadIdx.x >> 6);
    const float ui = u[row];
    const float f  = F[(size_t)row * CD + lane];
    const float yv = f * ui;
    const unsigned short h = f2bf(yv);
    const int yo = yperm_off(row, lane);
    Yph[yo] = h;
    Ypl[yo] = f2bf(yv - bf2f(h));
    Fp[fperm_off(row, lane)] = f2bf(f);
    float s2 = yv * yv;
    #pragma unroll
    for (int o = 32; o > 0; o >>= 1) s2 += __shfl_xor(s2, o, 64);
    if (lane == 0) squ[row] = make_float2(s2, 0.5f * ui);
}

// ---------------- fused MFMA flash pass ----------------
// grid (64, 32). 4 waves x 16 i-rows. All Y/F fragment loads are 1KB contiguous
// per wave instruction (permuted global layouts). No barriers.
template<bool ABF>
__global__ __launch_bounds__(256, 4) void k_fused(
    const float* __restrict__ A, const unsigned short* __restrict__ Abf,
    const unsigned short* __restrict__ Yph, const unsigned short* __restrict__ Ypl,
    const unsigned short* __restrict__ Fp, const float2* __restrict__ squ,
    const float* __restrict__ log_lams, const int k,
    float* __restrict__ partF, float* __restrict__ partQ)
{
    __shared__ __align__(16) unsigned short w_lds[4][16][72];
    const int tid = threadIdx.x, lane = tid & 63, wid = tid >> 6;
    const int m = lane & 15, b = lane >> 4;
    const int I0 = blockIdx.x * 64, js = blockIdx.y;

    const float lam   = __expf(log_lams[k]);
    const float invA1 = 1.0f / (SCAD_Af - 1.0f);
    const float c1    = SCAD_Af * lam * invA1;

    // Yi A-fragments (fragment layout: lane-contiguous)
    const size_t ybase = ((size_t)blockIdx.x * 8 + wid * 2) * 512 + (size_t)lane * 8;
    const bf16x8 yiH0 = *(const bf16x8*)(Yph + ybase);
    const bf16x8 yiH1 = *(const bf16x8*)(Yph + ybase + 512);
    const bf16x8 yiL0 = *(const bf16x8*)(Ypl + ybase);
    const bf16x8 yiL1 = *(const bf16x8*)(Ypl + ybase + 512);

    float sqi_r[4];
    #pragma unroll
    for (int reg = 0; reg < 4; ++reg)
        sqi_r[reg] = squ[I0 + 16*wid + 4*b + reg].x;

    f32x4 FV[4];
    #pragma unroll
    for (int ct = 0; ct < 4; ++ct) FV[ct] = (f32x4){0.f, 0.f, 0.f, 0.f};
    float qa[4] = {0.f, 0.f, 0.f, 0.f};

    // A-tile fragment base (permuted layout): lane-contiguous 32B
    const size_t afrag_off = (size_t)(64*wid + 16*b + m) * 16;
    bf16x8 aC0, aC1, aN0, aN1;
    if constexpr (ABF) {
        const size_t tb = ((size_t)blockIdx.x * 64 + (size_t)(js * JT_PER)) * 4096 + afrag_off;
        aC0 = *(const bf16x8*)(Abf + tb);
        aC1 = *(const bf16x8*)(Abf + tb + 8);
    }

    for (int jt = 0; jt < JT_PER; ++jt) {
        const int J0 = js * (64 * JT_PER) + jt * 64;
        const int Jt = J0 >> 6;

        if constexpr (ABF) {
            if (jt + 1 < JT_PER) {     // prefetch next A tile fragment
                const size_t tb = ((size_t)blockIdx.x * 64 + (size_t)(js * JT_PER + jt + 1)) * 4096 + afrag_off;
                aN0 = *(const bf16x8*)(Abf + tb);
                aN1 = *(const bf16x8*)(Abf + tb + 8);
            }
        }

        float sqj[4], ujh[4];
        #pragma unroll
        for (int ct = 0; ct < 4; ++ct) {
            const float2 s = squ[J0 + 16*ct + m];
            sqj[ct] = s.x; ujh[ct] = s.y;
        }

        // Gram: G[i][j] = Yi . Yj (hi/lo split, lo*lo dropped)
        f32x4 g[4];
        #pragma unroll
        for (int ct = 0; ct < 4; ++ct) {
            const size_t jb = ((size_t)Jt * 8 + ct * 2) * 512 + (size_t)lane * 8;
            const bf16x8 bh0 = *(const bf16x8*)(Yph + jb);
            const bf16x8 bh1 = *(const bf16x8*)(Yph + jb + 512);
            const bf16x8 bl0 = *(const bf16x8*)(Ypl + jb);
            const bf16x8 bl1 = *(const bf16x8*)(Ypl + jb + 512);
            f32x4 acc = (f32x4){0.f, 0.f, 0.f, 0.f};
            acc = MFMA16(yiH0, bh0, acc);
            acc = MFMA16(yiH1, bh1, acc);
            acc = MFMA16(yiH0, bl0, acc);
            acc = MFMA16(yiH1, bl1, acc);
            acc = MFMA16(yiL0, bh0, acc);
            acc = MFMA16(yiL1, bh1, acc);
            g[ct] = acc;
        }

        // A values for this tile
        float av[4][4];
        if constexpr (ABF) {
            #pragma unroll
            for (int reg = 0; reg < 4; ++reg) {
                av[reg][0] = bf2f((unsigned short)aC0[reg]);
                av[reg][1] = bf2f((unsigned short)aC0[4 + reg]);
                av[reg][2] = bf2f((unsigned short)aC1[reg]);
                av[reg][3] = bf2f((unsigned short)aC1[4 + reg]);
            }
        } else {
            #pragma unroll
            for (int reg = 0; reg < 4; ++reg) {
                const size_t arb = (size_t)(I0 + 16*wid + 4*b + reg) * NN + J0 + m;
                #pragma unroll
                for (int ct = 0; ct < 4; ++ct)
                    av[reg][ct] = A[arb + 16*ct];
            }
        }

        const bool diag = (J0 == I0);

        // SCAD weight + q accumulation + w -> LDS (bf16)
        #pragma unroll
        for (int ct = 0; ct < 4; ++ct) {
            #pragma unroll
            for (int reg = 0; reg < 4; ++reg) {
                const float Z   = fmaf(-2.0f, g[ct][reg], sqi_r[reg] + sqj[ct]);
                const float Zp  = fmaxf(Z, 0.0f) + DIST_EPSf;
                const float rsq = __builtin_amdgcn_rsqf(Zp);
                const float y   = Zp * rsq;                         // sqrt(Zp)
                const float t1  = fmaf(-invA1, y, c1);              // (a*lam-y)/(a-1)
                const float rho = __builtin_amdgcn_fmed3f(t1, 0.0f, lam);
                const float wv  = fminf(rho * rsq, 2.0f);           // 2*min(rho/(2y),1)
                float aij = av[reg][ct];
                if (diag && ct == wid && m == 4*b + reg) aij += 1.0f;
                const float t = wv * aij * ujh[ct];                 // w*(A+I)*u_j
                qa[reg] += t;
                w_lds[wid][4*b + reg][m + 16*ct] = f2bf(t);
            }
        }

        // PV: FV[i][c] += w[i][j] * F[j][c]  (Fp fragment layout, contiguous loads)
        #pragma unroll
        for (int ks = 0; ks < 2; ++ks) {
            const bf16x8 wf = *(const bf16x8*)&w_lds[wid][m][8*b + 32*ks];
            #pragma unroll
            for (int ct = 0; ct < 4; ++ct) {
                const bf16x8 ff = *(const bf16x8*)(Fp +
                    ((size_t)Jt * 8 + ct * 2 + ks) * 512 + (size_t)lane * 8);
                FV[ct] = MFMA16(wf, ff, FV[ct]);
            }
        }

        if constexpr (ABF) { aC0 = aN0; aC1 = aN1; }
    }

    // write partials
    const size_t base = (size_t)js * NN + I0 + 16*wid;
    #pragma unroll
    for (int ct = 0; ct < 4; ++ct)
        #pragma unroll
        for (int reg = 0; reg < 4; ++reg)
            partF[(base + 4*b + reg) * CD + m + 16*ct] = FV[ct][reg];

    #pragma unroll
    for (int reg = 0; reg < 4; ++reg) {
        float q = qa[reg];
        q += __shfl_xor(q, 1, 64);
        q += __shfl_xor(q, 2, 64);
        q += __shfl_xor(q, 4, 64);
        q += __shfl_xor(q, 8, 64);
        if (m == 0) partQ[base + 4*b + reg] = q;
    }
}

// ---------------- combine partials -> F_new, prep next-iter fragment buffers ----------------
__global__ __launch_bounds__(256) void k_combine(
    const float* __restrict__ partF, const float* __restrict__ partQ,
    const float* __restrict__ F0, const float* __restrict__ lam_node,
    const float* __restrict__ u, float* __restrict__ Fout,
    unsigned short* __restrict__ Yph, unsigned short* __restrict__ Ypl,
    unsigned short* __restrict__ Fp, float2* __restrict__ squ)
{
    const int lane = threadIdx.x & 63;
    const int row  = blockIdx.x * 4 + (threadIdx.x >> 6);
    float acc = 0.0f, q = 0.0f;
    #pragma unroll
    for (int s = 0; s < NSPLIT; ++s) {
        acc += partF[((size_t)s * NN + row) * CD + lane];
        q   += partQ[(size_t)s * NN + row];
    }
    const float ui = u[row];
    const float ln = lam_node[row];
    const float f0 = F0[(size_t)row * CD + lane];
    const float fn = (acc * ui + ln * f0) / (q * ui + ln);
    Fout[(size_t)row * CD + lane] = fn;
    const float yv = fn * ui;
    const unsigned short h = f2bf(yv);
    const int yo = yperm_off(row, lane);
    Yph[yo] = h;
    Ypl[yo] = f2bf(yv - bf2f(h));
    Fp[fperm_off(row, lane)] = f2bf(fn);
    float s2 = yv * yv;
    #pragma unroll
    for (int o = 32; o > 0; o >>= 1) s2 += __shfl_xor(s2, o, 64);
    if (lane == 0) squ[row] = make_float2(s2, 0.5f * ui);
}

extern "C" void kernel_launch(void* const* d_in, const int* in_sizes, int n_in,
                              void* d_out, int out_size, void* d_ws, size_t ws_size,
                              hipStream_t stream)
{
    const float* A         = (const float*)d_in[0];
    const float* X         = (const float*)d_in[1];
    const float* W1        = (const float*)d_in[2];
    const float* b1        = (const float*)d_in[3];
    const float* W2        = (const float*)d_in[4];
    const float* b2        = (const float*)d_in[5];
    const float* log_lams  = (const float*)d_in[6];
    const float* raw_alpha = (const float*)d_in[7];
    float* out = (float*)d_out;

    char* p = (char*)d_ws;
    auto alloc = [&](size_t bytes) -> char* {
        char* r = p;
        p += (bytes + 255) & ~(size_t)255;
        return r;
    };
    float* Hid      = (float*)alloc((size_t)NN * HID * 4);
    float* F0       = (float*)alloc((size_t)NN * CD * 4);
    float* raw_lam  = (float*)alloc((size_t)NN * 4);
    float* lam_node = (float*)alloc((size_t)NN * 4);
    float* uvec     = (float*)alloc((size_t)NN * 4);
    float2* squ     = (float2*)alloc((size_t)NN * 8);
    float* Fbuf     = (float*)alloc((size_t)NN * CD * 4);
    unsigned short* Yph = (unsigned short*)alloc((size_t)NN * CD * 2);
    unsigned short* Ypl = (unsigned short*)alloc((size_t)NN * CD * 2);
    unsigned short* Fp  = (unsigned short*)alloc((size_t)NN * CD * 2);
    float* partF    = (float*)alloc((size_t)NSPLIT * NN * CD * 4);
    float* partQ    = (float*)alloc((size_t)NSPLIT * NN * 4);
    const size_t base_used = (size_t)(p - (char*)d_ws);
    const size_t abf_bytes = (size_t)NN * NN * 2;
    const bool use_abf = (ws_size >= base_used + abf_bytes + 4096);
    unsigned short* Abf = use_abf ? (unsigned short*)alloc(abf_bytes) : (unsigned short*)nullptr;

    k_gemm1<<<dim3(64, 4), 256, 0, stream>>>(X, W1, b1, Hid);
    k_gemm2<<<dim3(64),    256, 0, stream>>>(Hid, W2, b2, F0);
    k_conf <<<dim3(1024),  256, 0, stream>>>(F0, raw_alpha, raw_lam);
    k_lam  <<<dim3(1),     256, 0, stream>>>(raw_lam, lam_node);
    k_deg  <<<dim3(4096),  256, 0, stream>>>(A, uvec);
    k_prep <<<dim3(1024),  256, 0, stream>>>(F0, uvec, Yph, Ypl, Fp, squ);
    if (use_abf)
        k_castA<<<dim3(4096), 256, 0, stream>>>(A, Abf);

    for (int k = 0; k < 10; ++k) {
        float* Fout = (k == 9) ? out : Fbuf;
        if (use_abf)
            k_fused<true><<<dim3(64, NSPLIT), 256, 0, stream>>>(A, Abf, Yph, Ypl, Fp,
                squ, log_lams, k, partF, partQ);
        else
            k_fused<false><<<dim3(64, NSPLIT), 256, 0, stream>>>(A, Abf, Yph, Ypl, Fp,
                squ, log_lams, k, partF, partQ);
        k_combine<<<dim3(1024), 256, 0, stream>>>(partF, partQ, F0, lam_node, uvec,
                                                  Fout, Yph, Ypl, Fp, squ);
    }
}

// Round 9
// 528.421 us; speedup vs baseline: 2.3395x; 1.0428x over previous
//
#include <hip/hip_runtime.h>
#include <hip/hip_fp16.h>
#include <math.h>

// RUNG confidence-lambda QN-IRLS, round 9:
//  - partials in packed fp16 (fragment order): fused stores 8x256B coalesced,
//    combine input halved (33.5 -> 16.8 MB/iter)
//  - deg fused into castA (one fewer 67MB pass over A)
// k_fused math/layout otherwise identical to r8.

#define NN 4096
#define DIN 512
#define HID 256
#define CD 64
#define NSPLIT 32
#define JT_PER 2   // (NN/NSPLIT)/64

static constexpr float SCAD_Af   = 3.7f;
static constexpr float EPSf      = 1e-6f;
static constexpr float DIST_EPSf = 1e-8f;
#define LAM_BASEF ((float)(1.0 / 0.9 - 1.0))

typedef __attribute__((ext_vector_type(8))) short bf16x8;
typedef __attribute__((ext_vector_type(4))) float f32x4;

#define MFMA16(a, b, c) __builtin_amdgcn_mfma_f32_16x16x32_bf16((a), (b), (c), 0, 0, 0)

__device__ inline unsigned short f2bf(float f) {
    unsigned u = __float_as_uint(f);
    u += 0x7FFFu + ((u >> 16) & 1u);          // RNE
    return (unsigned short)(u >> 16);
}
__device__ inline float bf2f(unsigned short h) {
    return __uint_as_float(((unsigned)h) << 16);
}

// Permuted Y layout: Yp[(tile*8 + ct*2 + h)*512 + (b*16+m)*8 + e]
__device__ inline int yperm_off(int row, int c) {
    const int tile = row >> 6, ct = (row >> 4) & 3, m = row & 15;
    return (tile * 8 + ct * 2 + (c >> 5)) * 512 + ((c >> 3) & 3) * 128 + m * 8 + (c & 7);
}
// Permuted F layout (PV B-fragment order)
__device__ inline int fperm_off(int row, int c) {
    const int tile = row >> 6;
    return (tile * 8 + (c >> 4) * 2 + ((row >> 5) & 1)) * 512
         + (((row >> 3) & 3) * 16 + (c & 15)) * 8 + (row & 7);
}

// ---------------- GEMM1: Hid = relu(X @ W1 + b1) ----------------
__global__ __launch_bounds__(256) void k_gemm1(const float* __restrict__ X,
    const float* __restrict__ W1, const float* __restrict__ b1,
    float* __restrict__ Hid)
{
    __shared__ float Xs[16][68];
    __shared__ float Ws[16][68];
    const int tid = threadIdx.x;
    const int tx = tid & 15, ty = tid >> 4;
    const int M0 = blockIdx.x * 64, N0 = blockIdx.y * 64;
    float acc[4][4] = {};
    for (int k0 = 0; k0 < DIN; k0 += 16) {
        __syncthreads();
        {
            const int kk = tid & 15, mm = tid >> 4;
            #pragma unroll
            for (int r = 0; r < 4; ++r)
                Xs[kk][mm + 16*r] = X[(size_t)(M0 + mm + 16*r) * DIN + k0 + kk];
            const int n = tid & 63, kw = tid >> 6;
            #pragma unroll
            for (int r = 0; r < 4; ++r)
                Ws[kw + 4*r][n] = W1[(size_t)(k0 + kw + 4*r) * HID + N0 + n];
        }
        __syncthreads();
        #pragma unroll
        for (int kk = 0; kk < 16; ++kk) {
            const float4 av = *(const float4*)&Xs[kk][4*ty];
            const float4 bv = *(const float4*)&Ws[kk][4*tx];
            const float a[4] = {av.x, av.y, av.z, av.w};
            const float b[4] = {bv.x, bv.y, bv.z, bv.w};
            #pragma unroll
            for (int i = 0; i < 4; ++i)
                #pragma unroll
                for (int j = 0; j < 4; ++j)
                    acc[i][j] = fmaf(a[i], b[j], acc[i][j]);
        }
    }
    #pragma unroll
    for (int i = 0; i < 4; ++i)
        #pragma unroll
        for (int j = 0; j < 4; ++j) {
            const int gn = N0 + 4*tx + j;
            const float v = acc[i][j] + b1[gn];
            Hid[(size_t)(M0 + 4*ty + i) * HID + gn] = fmaxf(v, 0.0f);
        }
}

// ---------------- GEMM2: F0 = Hid @ W2 + b2 ----------------
__global__ __launch_bounds__(256) void k_gemm2(const float* __restrict__ Hd,
    const float* __restrict__ W2, const float* __restrict__ b2,
    float* __restrict__ F0)
{
    __shared__ float Hs[16][68];
    __shared__ float Ws[16][68];
    const int tid = threadIdx.x;
    const int tx = tid & 15, ty = tid >> 4;
    const int M0 = blockIdx.x * 64;
    float acc[4][4] = {};
    for (int k0 = 0; k0 < HID; k0 += 16) {
        __syncthreads();
        {
            const int kk = tid & 15, mm = tid >> 4;
            #pragma unroll
            for (int r = 0; r < 4; ++r)
                Hs[kk][mm + 16*r] = Hd[(size_t)(M0 + mm + 16*r) * HID + k0 + kk];
            const int n = tid & 63, kw = tid >> 6;
            #pragma unroll
            for (int r = 0; r < 4; ++r)
                Ws[kw + 4*r][n] = W2[(size_t)(k0 + kw + 4*r) * CD + n];
        }
        __syncthreads();
        #pragma unroll
        for (int kk = 0; kk < 16; ++kk) {
            const float4 av = *(const float4*)&Hs[kk][4*ty];
            const float4 bv = *(const float4*)&Ws[kk][4*tx];
            const float a[4] = {av.x, av.y, av.z, av.w};
            const float b[4] = {bv.x, bv.y, bv.z, bv.w};
            #pragma unroll
            for (int i = 0; i < 4; ++i)
                #pragma unroll
                for (int j = 0; j < 4; ++j)
                    acc[i][j] = fmaf(a[i], b[j], acc[i][j]);
        }
    }
    #pragma unroll
    for (int i = 0; i < 4; ++i)
        #pragma unroll
        for (int j = 0; j < 4; ++j) {
            const int gn = 4*tx + j;
            F0[(size_t)(M0 + 4*ty + i) * CD + gn] = acc[i][j] + b2[gn];
        }
}

// ---------------- conf -> raw_lam ----------------
__global__ __launch_bounds__(256) void k_conf(const float* __restrict__ F0,
    const float* __restrict__ raw_alpha, float* __restrict__ raw_lam)
{
    const int lane = threadIdx.x & 63;
    const int row  = blockIdx.x * 4 + (threadIdx.x >> 6);
    const float alpha = log1pf(expf(raw_alpha[0])) + 0.5f;
    const float f = F0[(size_t)row * CD + lane];
    float m = f;
    #pragma unroll
    for (int o = 32; o > 0; o >>= 1) m = fmaxf(m, __shfl_xor(m, o, 64));
    float e = expf(f - m);
    #pragma unroll
    for (int o = 32; o > 0; o >>= 1) e += __shfl_xor(e, o, 64);
    float conf = 1.0f / e;
    conf = fminf(fmaxf(conf, EPSf), 1.0f - EPSf);
    const float rl = LAM_BASEF * powf(fmaxf(1.0f - conf, EPSf), alpha);
    if (lane == 0) raw_lam[row] = rl;
}

// ---------------- lam_node ----------------
__global__ __launch_bounds__(256) void k_lam(const float* __restrict__ raw_lam,
    float* __restrict__ lam_node)
{
    __shared__ float red[256];
    float s = 0.0f;
    for (int i = threadIdx.x; i < NN; i += 256) s += raw_lam[i];
    red[threadIdx.x] = s;
    __syncthreads();
    for (int o = 128; o > 0; o >>= 1) {
        if (threadIdx.x < o) red[threadIdx.x] += red[threadIdx.x + o];
        __syncthreads();
    }
    const float mean  = red[0] * (1.0f / NN);
    const float scale = LAM_BASEF / fmaxf(mean, EPSf);
    for (int i = threadIdx.x; i < NN; i += 256)
        lam_node[i] = fmaxf(raw_lam[i] * scale, EPSf);
}

// ---------------- deg (fallback path, !use_abf): u = 1/sqrt(rowsum(A)+1) ------
__global__ __launch_bounds__(256) void k_deg(const float* __restrict__ A,
    float* __restrict__ u)
{
    __shared__ float red[256];
    const int i = blockIdx.x;
    float s = 0.0f;
    for (int j = threadIdx.x; j < NN; j += 256) s += A[(size_t)i * NN + j];
    red[threadIdx.x] = s;
    __syncthreads();
    for (int o = 128; o > 0; o >>= 1) {
        if (threadIdx.x < o) red[threadIdx.x] += red[threadIdx.x + o];
        __syncthreads();
    }
    if (threadIdx.x == 0) u[i] = 1.0f / sqrtf(red[0] + 1.0f);
}

// ---------------- fused A->bf16 permuted cast + per-row deg partials ----------
__global__ __launch_bounds__(256) void k_castA_deg(const float* __restrict__ A,
    unsigned short* __restrict__ Abf, float* __restrict__ deg)
{
    __shared__ unsigned short t_lds[4096];
    __shared__ float rsum[64][4];
    const int ti = blockIdx.x >> 6, tj = blockIdx.x & 63;
    const int t = threadIdx.x;
    const int r = t >> 2, cq = t & 3;
    const size_t arow = (size_t)(ti * 64 + r) * NN + tj * 64 + cq * 16;
    float s = 0.0f;
    #pragma unroll
    for (int q = 0; q < 4; ++q) {
        const float4 v = *(const float4*)(A + arow + 4 * q);
        const float vv[4] = {v.x, v.y, v.z, v.w};
        s += vv[0] + vv[1] + vv[2] + vv[3];
        #pragma unroll
        for (int e = 0; e < 4; ++e) {
            const int cc = 4 * q + e;
            const int pos = ((r >> 2) * 16 + cc) * 16 + cq * 4 + (r & 3);
            t_lds[pos] = f2bf(vv[e]);
        }
    }
    rsum[r][cq] = s;
    __syncthreads();
    const uint4* src = (const uint4*)&t_lds[t * 16];
    uint4* dst = (uint4*)(Abf + (size_t)blockIdx.x * 4096 + t * 16);
    dst[0] = src[0];
    dst[1] = src[1];
    if (t < 64) {
        const float d = rsum[t][0] + rsum[t][1] + rsum[t][2] + rsum[t][3];
        atomicAdd(&deg[ti * 64 + t], d);
    }
}

// ---------------- deg -> u ----------------
__global__ __launch_bounds__(256) void k_u(const float* __restrict__ deg,
    float* __restrict__ u)
{
    const int i = blockIdx.x * 256 + threadIdx.x;
    u[i] = 1.0f / sqrtf(deg[i] + 1.0f);
}

// ---------------- prep: F0 -> Yp(hi/lo), Fp, squ ----------------
__global__ __launch_bounds__(256) void k_prep(const float* __restrict__ F,
    const float* __restrict__ u, unsigned short* __restrict__ Yph,
    unsigned short* __restrict__ Ypl, unsigned short* __restrict__ Fp,
    float2* __restrict__ squ)
{
    const int lane = threadIdx.x & 63;
    const int row  = blockIdx.x * 4 + (threadIdx.x >> 6);
    const float ui = u[row];
    const float f  = F[(size_t)row * CD + lane];
    const float yv = f * ui;
    const unsigned short h = f2bf(yv);
    const int yo = yperm_off(row, lane);
    Yph[yo] = h;
    Ypl[yo] = f2bf(yv - bf2f(h));
    Fp[fperm_off(row, lane)] = f2bf(f);
    float s2 = yv * yv;
    #pragma unroll
    for (int o = 32; o > 0; o >>= 1) s2 += __shfl_xor(s2, o, 64);
    if (lane == 0) squ[row] = make_float2(s2, 0.5f * ui);
}

// ---------------- fused MFMA flash pass ----------------
// grid (64, 32). 4 waves x 16 i-rows. Partials written as packed fp16 in
// fragment order: 8 x 256B coalesced dword stores per wave.
template<bool ABF>
__global__ __launch_bounds__(256, 4) void k_fused(
    const float* __restrict__ A, const unsigned short* __restrict__ Abf,
    const unsigned short* __restrict__ Yph, const unsigned short* __restrict__ Ypl,
    const unsigned short* __restrict__ Fp, const float2* __restrict__ squ,
    const float* __restrict__ log_lams, const int k,
    unsigned* __restrict__ partH, float* __restrict__ partQ)
{
    __shared__ __align__(16) unsigned short w_lds[4][16][72];
    const int tid = threadIdx.x, lane = tid & 63, wid = tid >> 6;
    const int m = lane & 15, b = lane >> 4;
    const int I0 = blockIdx.x * 64, js = blockIdx.y;

    const float lam   = __expf(log_lams[k]);
    const float invA1 = 1.0f / (SCAD_Af - 1.0f);
    const float c1    = SCAD_Af * lam * invA1;

    const size_t ybase = ((size_t)blockIdx.x * 8 + wid * 2) * 512 + (size_t)lane * 8;
    const bf16x8 yiH0 = *(const bf16x8*)(Yph + ybase);
    const bf16x8 yiH1 = *(const bf16x8*)(Yph + ybase + 512);
    const bf16x8 yiL0 = *(const bf16x8*)(Ypl + ybase);
    const bf16x8 yiL1 = *(const bf16x8*)(Ypl + ybase + 512);

    float sqi_r[4];
    #pragma unroll
    for (int reg = 0; reg < 4; ++reg)
        sqi_r[reg] = squ[I0 + 16*wid + 4*b + reg].x;

    f32x4 FV[4];
    #pragma unroll
    for (int ct = 0; ct < 4; ++ct) FV[ct] = (f32x4){0.f, 0.f, 0.f, 0.f};
    float qa[4] = {0.f, 0.f, 0.f, 0.f};

    const size_t afrag_off = (size_t)(64*wid + 16*b + m) * 16;
    bf16x8 aC0, aC1, aN0, aN1;
    if constexpr (ABF) {
        const size_t tb = ((size_t)blockIdx.x * 64 + (size_t)(js * JT_PER)) * 4096 + afrag_off;
        aC0 = *(const bf16x8*)(Abf + tb);
        aC1 = *(const bf16x8*)(Abf + tb + 8);
    }

    for (int jt = 0; jt < JT_PER; ++jt) {
        const int J0 = js * (64 * JT_PER) + jt * 64;
        const int Jt = J0 >> 6;

        if constexpr (ABF) {
            if (jt + 1 < JT_PER) {
                const size_t tb = ((size_t)blockIdx.x * 64 + (size_t)(js * JT_PER + jt + 1)) * 4096 + afrag_off;
                aN0 = *(const bf16x8*)(Abf + tb);
                aN1 = *(const bf16x8*)(Abf + tb + 8);
            }
        }

        float sqj[4], ujh[4];
        #pragma unroll
        for (int ct = 0; ct < 4; ++ct) {
            const float2 s = squ[J0 + 16*ct + m];
            sqj[ct] = s.x; ujh[ct] = s.y;
        }

        // Gram (hi/lo split, lo*lo dropped)
        f32x4 g[4];
        #pragma unroll
        for (int ct = 0; ct < 4; ++ct) {
            const size_t jb = ((size_t)Jt * 8 + ct * 2) * 512 + (size_t)lane * 8;
            const bf16x8 bh0 = *(const bf16x8*)(Yph + jb);
            const bf16x8 bh1 = *(const bf16x8*)(Yph + jb + 512);
            const bf16x8 bl0 = *(const bf16x8*)(Ypl + jb);
            const bf16x8 bl1 = *(const bf16x8*)(Ypl + jb + 512);
            f32x4 acc = (f32x4){0.f, 0.f, 0.f, 0.f};
            acc = MFMA16(yiH0, bh0, acc);
            acc = MFMA16(yiH1, bh1, acc);
            acc = MFMA16(yiH0, bl0, acc);
            acc = MFMA16(yiH1, bl1, acc);
            acc = MFMA16(yiL0, bh0, acc);
            acc = MFMA16(yiL1, bh1, acc);
            g[ct] = acc;
        }

        float av[4][4];
        if constexpr (ABF) {
            #pragma unroll
            for (int reg = 0; reg < 4; ++reg) {
                av[reg][0] = bf2f((unsigned short)aC0[reg]);
                av[reg][1] = bf2f((unsigned short)aC0[4 + reg]);
                av[reg][2] = bf2f((unsigned short)aC1[reg]);
                av[reg][3] = bf2f((unsigned short)aC1[4 + reg]);
            }
        } else {
            #pragma unroll
            for (int reg = 0; reg < 4; ++reg) {
                const size_t arb = (size_t)(I0 + 16*wid + 4*b + reg) * NN + J0 + m;
                #pragma unroll
                for (int ct = 0; ct < 4; ++ct)
                    av[reg][ct] = A[arb + 16*ct];
            }
        }

        const bool diag = (J0 == I0);

        // SCAD weight + q accumulation + w -> LDS (bf16)
        #pragma unroll
        for (int ct = 0; ct < 4; ++ct) {
            #pragma unroll
            for (int reg = 0; reg < 4; ++reg) {
                const float Z   = fmaf(-2.0f, g[ct][reg], sqi_r[reg] + sqj[ct]);
                const float Zp  = fmaxf(Z, 0.0f) + DIST_EPSf;
                const float rsq = __builtin_amdgcn_rsqf(Zp);
                const float y   = Zp * rsq;
                const float t1  = fmaf(-invA1, y, c1);
                const float rho = __builtin_amdgcn_fmed3f(t1, 0.0f, lam);
                const float wv  = fminf(rho * rsq, 2.0f);
                float aij = av[reg][ct];
                if (diag && ct == wid && m == 4*b + reg) aij += 1.0f;
                const float t = wv * aij * ujh[ct];
                qa[reg] += t;
                w_lds[wid][4*b + reg][m + 16*ct] = f2bf(t);
            }
        }

        // PV
        #pragma unroll
        for (int ks = 0; ks < 2; ++ks) {
            const bf16x8 wf = *(const bf16x8*)&w_lds[wid][m][8*b + 32*ks];
            #pragma unroll
            for (int ct = 0; ct < 4; ++ct) {
                const bf16x8 ff = *(const bf16x8*)(Fp +
                    ((size_t)Jt * 8 + ct * 2 + ks) * 512 + (size_t)lane * 8);
                FV[ct] = MFMA16(wf, ff, FV[ct]);
            }
        }

        if constexpr (ABF) { aC0 = aN0; aC1 = aN1; }
    }

    // write partials: packed fp16, fragment order, fully coalesced
    const size_t wb = ((((size_t)js * 64 + blockIdx.x) * 4 + wid) * 8) * 64 + lane;
    #pragma unroll
    for (int ct = 0; ct < 4; ++ct)
        #pragma unroll
        for (int h = 0; h < 2; ++h) {
            const __half2 pk = __floats2half2_rn(FV[ct][2*h], FV[ct][2*h + 1]);
            partH[wb + (size_t)(ct * 2 + h) * 64] = *(const unsigned*)&pk;
        }

    const size_t qbase = (size_t)js * NN + I0 + 16*wid;
    #pragma unroll
    for (int reg = 0; reg < 4; ++reg) {
        float q = qa[reg];
        q += __shfl_xor(q, 1, 64);
        q += __shfl_xor(q, 2, 64);
        q += __shfl_xor(q, 4, 64);
        q += __shfl_xor(q, 8, 64);
        if (m == 0) partQ[qbase + 4*b + reg] = q;
    }
}

// ---------------- combine partials -> F_new, prep next-iter fragment buffers ---
__global__ __launch_bounds__(256) void k_combine(
    const unsigned* __restrict__ partH, const float* __restrict__ partQ,
    const float* __restrict__ F0, const float* __restrict__ lam_node,
    const float* __restrict__ u, float* __restrict__ Fout,
    unsigned short* __restrict__ Yph, unsigned short* __restrict__ Ypl,
    unsigned short* __restrict__ Fp, float2* __restrict__ squ)
{
    const int lane = threadIdx.x & 63;
    const int row  = blockIdx.x * 4 + (threadIdx.x >> 6);

    const int bi = row >> 6, wid = (row >> 4) & 3, bq = (row >> 2) & 3, reg = row & 3;
    const int ct = lane >> 4, m = lane & 15;
    const int hh = reg >> 1, p = reg & 1;
    const size_t boff = (((size_t)bi * 4 + wid) * 8 + ct * 2 + hh) * 64 + bq * 16 + m;

    float acc = 0.0f, q = 0.0f;
    #pragma unroll
    for (int s = 0; s < NSPLIT; ++s) {
        const unsigned v = partH[(size_t)s * (64 * 4 * 8 * 64) + boff];
        const __half2 hv = *(const __half2*)&v;
        acc += p ? __high2float(hv) : __low2float(hv);
        q   += partQ[(size_t)s * NN + row];
    }
    const float ui = u[row];
    const float ln = lam_node[row];
    const float f0 = F0[(size_t)row * CD + lane];
    const float fn = (acc * ui + ln * f0) / (q * ui + ln);
    Fout[(size_t)row * CD + lane] = fn;
    const float yv = fn * ui;
    const unsigned short h = f2bf(yv);
    const int yo = yperm_off(row, lane);
    Yph[yo] = h;
    Ypl[yo] = f2bf(yv - bf2f(h));
    Fp[fperm_off(row, lane)] = f2bf(fn);
    float s2 = yv * yv;
    #pragma unroll
    for (int o = 32; o > 0; o >>= 1) s2 += __shfl_xor(s2, o, 64);
    if (lane == 0) squ[row] = make_float2(s2, 0.5f * ui);
}

extern "C" void kernel_launch(void* const* d_in, const int* in_sizes, int n_in,
                              void* d_out, int out_size, void* d_ws, size_t ws_size,
                              hipStream_t stream)
{
    const float* A         = (const float*)d_in[0];
    const float* X         = (const float*)d_in[1];
    const float* W1        = (const float*)d_in[2];
    const float* b1        = (const float*)d_in[3];
    const float* W2        = (const float*)d_in[4];
    const float* b2        = (const float*)d_in[5];
    const float* log_lams  = (const float*)d_in[6];
    const float* raw_alpha = (const float*)d_in[7];
    float* out = (float*)d_out;

    char* p = (char*)d_ws;
    auto alloc = [&](size_t bytes) -> char* {
        char* r = p;
        p += (bytes + 255) & ~(size_t)255;
        return r;
    };
    float* Hid      = (float*)alloc((size_t)NN * HID * 4);
    float* F0       = (float*)alloc((size_t)NN * CD * 4);
    float* raw_lam  = (float*)alloc((size_t)NN * 4);
    float* lam_node = (float*)alloc((size_t)NN * 4);
    float* uvec     = (float*)alloc((size_t)NN * 4);
    float* degacc   = (float*)alloc((size_t)NN * 4);
    float2* squ     = (float2*)alloc((size_t)NN * 8);
    float* Fbuf     = (float*)alloc((size_t)NN * CD * 4);
    unsigned short* Yph = (unsigned short*)alloc((size_t)NN * CD * 2);
    unsigned short* Ypl = (unsigned short*)alloc((size_t)NN * CD * 2);
    unsigned short* Fp  = (unsigned short*)alloc((size_t)NN * CD * 2);
    unsigned* partH = (unsigned*)alloc((size_t)NSPLIT * NN * CD * 2);
    float* partQ    = (float*)alloc((size_t)NSPLIT * NN * 4);
    const size_t base_used = (size_t)(p - (char*)d_ws);
    const size_t abf_bytes = (size_t)NN * NN * 2;
    const bool use_abf = (ws_size >= base_used + abf_bytes + 4096);
    unsigned short* Abf = use_abf ? (unsigned short*)alloc(abf_bytes) : (unsigned short*)nullptr;

    k_gemm1<<<dim3(64, 4), 256, 0, stream>>>(X, W1, b1, Hid);
    k_gemm2<<<dim3(64),    256, 0, stream>>>(Hid, W2, b2, F0);
    k_conf <<<dim3(1024),  256, 0, stream>>>(F0, raw_alpha, raw_lam);
    k_lam  <<<dim3(1),     256, 0, stream>>>(raw_lam, lam_node);
    if (use_abf) {
        hipMemsetAsync(degacc, 0, (size_t)NN * 4, stream);
        k_castA_deg<<<dim3(4096), 256, 0, stream>>>(A, Abf, degacc);
        k_u<<<dim3(16), 256, 0, stream>>>(degacc, uvec);
    } else {
        k_deg<<<dim3(4096), 256, 0, stream>>>(A, uvec);
    }
    k_prep <<<dim3(1024),  256, 0, stream>>>(F0, uvec, Yph, Ypl, Fp, squ);

    for (int k = 0; k < 10; ++k) {
        float* Fout = (k == 9) ? out : Fbuf;
        if (use_abf)
            k_fused<true><<<dim3(64, NSPLIT), 256, 0, stream>>>(A, Abf, Yph, Ypl, Fp,
                squ, log_lams, k, partH, partQ);
        else
            k_fused<false><<<dim3(64, NSPLIT), 256, 0, stream>>>(A, Abf, Yph, Ypl, Fp,
                squ, log_lams, k, partH, partQ);
        k_combine<<<dim3(1024), 256, 0, stream>>>(partH, partQ, F0, lam_node, uvec,
                                                  Fout, Yph, Ypl, Fp, squ);
    }
}